// Round 4
// baseline (37905.774 us; speedup 1.0000x reference)
//
#include <hip/hip_runtime.h>

#define B_   8
#define N_   1024
#define C_   768
#define H_   12
#define HD_  64
#define BH_  96
#define SCALE_ 0.125f
#define NIT_ 5

// ---------------------------------------------------------------------------
// K1 tiled: qkv = x @ W_qkv + b_qkv (fp32), scattered into k/v [B,H,N,HD].
// grid (1536/64=24, 8192/64=128), block 256 (16x16 logical, 4x4 per thread).
// ---------------------------------------------------------------------------
__global__ __launch_bounds__(256)
void qkv_gemm(const float* __restrict__ X, const float* __restrict__ W,
              const float* __restrict__ bias,
              float* __restrict__ Kb, float* __restrict__ Vb)
{
    __shared__ float As[64][17];
    __shared__ float Bs[16][68];
    const int tid = threadIdx.x;
    const int tx = tid & 15, ty = tid >> 4;
    const int m0 = blockIdx.y * 64;
    const int c0 = blockIdx.x * 64;      // [0, 1536)
    const int ar = tid >> 2, ak4 = (tid & 3) << 2;
    const int bk = tid >> 4, bc4 = (tid & 15) << 2;

    float acc[4][4] = {};

    for (int kt = 0; kt < 48; ++kt) {
        __syncthreads();
        float4 av = *(const float4*)(X + (size_t)(m0 + ar) * C_ + kt * 16 + ak4);
        As[ar][ak4 + 0] = av.x; As[ar][ak4 + 1] = av.y;
        As[ar][ak4 + 2] = av.z; As[ar][ak4 + 3] = av.w;
        *(float4*)&Bs[bk][bc4] =
            *(const float4*)(W + (size_t)(kt * 16 + bk) * (2 * C_) + c0 + bc4);
        __syncthreads();
#pragma unroll
        for (int kk = 0; kk < 16; ++kk) {
            float a_[4];
#pragma unroll
            for (int i = 0; i < 4; ++i) a_[i] = As[4 * ty + i][kk];
            float4 b_ = *(const float4*)&Bs[kk][4 * tx];
#pragma unroll
            for (int i = 0; i < 4; ++i) {
                acc[i][0] += a_[i] * b_.x;
                acc[i][1] += a_[i] * b_.y;
                acc[i][2] += a_[i] * b_.z;
                acc[i][3] += a_[i] * b_.w;
            }
        }
    }

    const int cbase = c0 + 4 * tx;               // within [c0, c0+64)
    const int h = (c0 % C_) >> 6;                // head is constant per block
    float* tgt = (c0 < C_) ? Kb : Vb;
    const float b0 = bias[cbase + 0], b1 = bias[cbase + 1];
    const float b2 = bias[cbase + 2], b3 = bias[cbase + 3];
#pragma unroll
    for (int i = 0; i < 4; ++i) {
        int m = m0 + 4 * ty + i;
        int b = m >> 10, n = m & 1023;
        float4 o;
        o.x = acc[i][0] + b0;
        o.y = acc[i][1] + b1;
        o.z = acc[i][2] + b2;
        o.w = acc[i][3] + b3;
        *(float4*)(tgt + ((size_t)(b * H_ + h) * N_ + n) * HD_ + 4 * tx) = o;
    }
}

// ---------------------------------------------------------------------------
// K2: mu[bh] = (N*C/4) / sum|k| per (b,h).
// ---------------------------------------------------------------------------
__global__ __launch_bounds__(256)
void musum(const float* __restrict__ Kb, float* __restrict__ mu)
{
    const int bh = blockIdx.x;
    const int tid = threadIdx.x;
    const float* p = Kb + (size_t)bh * (N_ * HD_);
    float s = 0.0f;
    for (int i = tid; i < N_ * HD_; i += 256) s += fabsf(p[i]);
    for (int off = 32; off; off >>= 1) s += __shfl_down(s, off, 64);
    __shared__ float red[4];
    if ((tid & 63) == 0) red[tid >> 6] = s;
    __syncthreads();
    if (tid == 0)
        mu[bh] = (float)(N_ * C_ / 4.0) / (red[0] + red[1] + red[2] + red[3]);
}

// ---------------------------------------------------------------------------
// K3: t = k - l + y/mu; s = soft_threshold(t, 4*mu); k2 = k - s - y/mu
// ---------------------------------------------------------------------------
__global__ __launch_bounds__(256)
void ew_sk2(const float* __restrict__ Kb, const float* __restrict__ Lb,
            const float* __restrict__ Yb, const float* __restrict__ mu,
            float* __restrict__ K2b)
{
    const int i = blockIdx.x * 256 + threadIdx.x;
    const int bh = i >> 16;
    const float m = mu[bh];
    const float lm = 4.0f * m;
    const float yom = Yb[i] / m;
    const float kv = Kb[i];
    const float t = kv - Lb[i] + yom;
    const float s = (t >= lm) ? (t - lm) : ((t <= -lm) ? (t + lm) : 0.0f);
    K2b[i] = kv - s - yom;
}

// ---------------------------------------------------------------------------
// K5: y_new = 2*y + mu*(k2 - l)
// ---------------------------------------------------------------------------
__global__ __launch_bounds__(256)
void ew_y(float* __restrict__ Yb, const float* __restrict__ K2b,
          const float* __restrict__ Lb, const float* __restrict__ mu)
{
    const int i = blockIdx.x * 256 + threadIdx.x;
    const int bh = i >> 16;
    const float m = mu[bh];
    Yb[i] = 2.0f * Yb[i] + m * (K2b[i] - Lb[i]);
}

// ---------------------------------------------------------------------------
// K4 flash v5: R0 structure (proven 485us) minus the Vs LDS stage.
//  - Q wave-private in LDS (no block barrier needed for it)
//  - K bulk-staged to LDS per tile (latency amortized, barrier-protected)
//  - Ps aliased onto Ks after S-compute (one barrier, then wave-private)
//  - V streamed from global with distance-1 register double-buffer; va
//    issued before softmax so its latency hides under VALU work
//  - LDS 34.8 KB -> 4 blocks/CU; m/z in registers
// FMA accumulation orders identical to R0 -> numerics preserved.
// grid (16, 96) x 256.
// ---------------------------------------------------------------------------
__global__ __launch_bounds__(256, 4)
void flash(const float* __restrict__ K2v, const float* __restrict__ Vv,
           float* __restrict__ Lout, float* __restrict__ Mrow,
           float* __restrict__ Zrow)
{
    __shared__ float Qs[64][68];
    __shared__ float Ks[64][68];          // doubles as Ps after S-compute

    const int tid = threadIdx.x;
    const int tx = tid & 15, ty = tid >> 4;
    const int bh = blockIdx.y;
    const int q0 = blockIdx.x * 64;
    const float* __restrict__ k2b = K2v + (size_t)bh * N_ * HD_;
    const float* __restrict__ vbp = Vv  + (size_t)bh * N_ * HD_;
    const int txo = 4 * tx;

    // Wave-private Q staging: wave w stages rows 16w..16w+15 (its own ty's).
    {
        const int r  = 4 * ty + (tx >> 2);
        const int c0 = (tx & 3) << 2;
#pragma unroll
        for (int c = 0; c < 4; ++c) {
            const int col = c0 + 16 * c;
            *(float4*)&Qs[r][col] =
                *(const float4*)(k2b + (size_t)(q0 + r) * HD_ + col);
        }
    }
    __builtin_amdgcn_wave_barrier();

    float m_run[4], z_run[4];
#pragma unroll
    for (int i = 0; i < 4; ++i) { m_run[i] = -1e30f; z_run[i] = 0.0f; }
    float O[4][4] = {};

    float4 va[4], vb4[4];
// V rows 4G..4G+3 of tile TILE, cols txo..txo+3.
#define LDV(BUF, TILE, G) do {                                               \
    const float* _p = vbp + ((TILE) << 12) + ((G) << 8) + txo;               \
    BUF[0] = *(const float4*)(_p);       BUF[1] = *(const float4*)(_p + 64); \
    BUF[2] = *(const float4*)(_p + 128); BUF[3] = *(const float4*)(_p + 192);\
} while (0)

    for (int kt = 0; kt < 16; ++kt) {
        __syncthreads();   // prev tile's Ps reads done before Ks restaged
        {
            int e = tid;
#pragma unroll
            for (int t = 0; t < 4; ++t, e += 256) {
                int r = e >> 4, c4 = (e & 15) << 2;
                *(float4*)&Ks[r][c4] =
                    *(const float4*)(k2b + (size_t)(kt * 64 + r) * HD_ + c4);
            }
        }
        __syncthreads();

        // S[i][j] = (Q row 4ty+i) . (K row tx+16j)   -- identical to R0
        float S[4][4] = {};
#pragma unroll 4
        for (int d4 = 0; d4 < 16; ++d4) {
            float4 a[4], b[4];
#pragma unroll
            for (int i = 0; i < 4; ++i) a[i] = *(const float4*)&Qs[4 * ty + i][4 * d4];
#pragma unroll
            for (int j = 0; j < 4; ++j) b[j] = *(const float4*)&Ks[tx + 16 * j][4 * d4];
#pragma unroll
            for (int i = 0; i < 4; ++i)
#pragma unroll
                for (int j = 0; j < 4; ++j)
                    S[i][j] += a[i].x * b[j].x + a[i].y * b[j].y +
                               a[i].z * b[j].z + a[i].w * b[j].w;
        }

        LDV(va, kt, 0);    // V group 0 in flight; softmax hides its latency

#pragma unroll
        for (int i = 0; i < 4; ++i)
#pragma unroll
            for (int j = 0; j < 4; ++j) S[i][j] *= SCALE_;

        float mt[4];
#pragma unroll
        for (int i = 0; i < 4; ++i)
            mt[i] = fmaxf(fmaxf(S[i][0], S[i][1]), fmaxf(S[i][2], S[i][3]));
        for (int off = 8; off; off >>= 1)
#pragma unroll
            for (int i = 0; i < 4; ++i)
                mt[i] = fmaxf(mt[i], __shfl_xor(mt[i], off, 16));

        float alpha[4], zs[4];
#pragma unroll
        for (int i = 0; i < 4; ++i) {
            const float mnew = fmaxf(m_run[i], mt[i]);
            alpha[i] = __expf(m_run[i] - mnew);
            m_run[i] = mnew;
            zs[i] = 0.0f;
#pragma unroll
            for (int j = 0; j < 4; ++j) {
                S[i][j] = __expf(S[i][j] - mnew);
                zs[i] += S[i][j];
            }
        }
        for (int off = 8; off; off >>= 1)
#pragma unroll
            for (int i = 0; i < 4; ++i) zs[i] += __shfl_xor(zs[i], off, 16);
#pragma unroll
        for (int i = 0; i < 4; ++i) {
            z_run[i] = z_run[i] * alpha[i] + zs[i];
#pragma unroll
            for (int j = 0; j < 4; ++j) O[i][j] *= alpha[i];
        }

        __syncthreads();   // all Ks reads complete before Ps overwrites it

#pragma unroll
        for (int i = 0; i < 4; ++i)
#pragma unroll
            for (int j = 0; j < 4; ++j)
                Ks[4 * ty + i][tx + 16 * j] = S[i][j];   // Ps := Ks storage
        __builtin_amdgcn_wave_barrier();   // own-wave rows: no block barrier

        // O[i][c] += sum_m Ps[4ty+i][m] * V[m][4tx+c], V from global,
        // distance-1 double buffer.  FMA order identical to R0.
#pragma unroll
        for (int g = 0; g < 16; g += 2) {
            LDV(vb4, kt, g + 1);
#pragma unroll
            for (int i = 0; i < 4; ++i) {
                const float4 pr = *(const float4*)&Ks[4 * ty + i][4 * g];
                O[i][0] += pr.x * va[0].x + pr.y * va[1].x + pr.z * va[2].x + pr.w * va[3].x;
                O[i][1] += pr.x * va[0].y + pr.y * va[1].y + pr.z * va[2].y + pr.w * va[3].y;
                O[i][2] += pr.x * va[0].z + pr.y * va[1].z + pr.z * va[2].z + pr.w * va[3].z;
                O[i][3] += pr.x * va[0].w + pr.y * va[1].w + pr.z * va[2].w + pr.w * va[3].w;
            }
            if (g + 2 < 16) LDV(va, kt, g + 2);
#pragma unroll
            for (int i = 0; i < 4; ++i) {
                const float4 pr = *(const float4*)&Ks[4 * ty + i][4 * (g + 1)];
                O[i][0] += pr.x * vb4[0].x + pr.y * vb4[1].x + pr.z * vb4[2].x + pr.w * vb4[3].x;
                O[i][1] += pr.x * vb4[0].y + pr.y * vb4[1].y + pr.z * vb4[2].y + pr.w * vb4[3].y;
                O[i][2] += pr.x * vb4[0].z + pr.y * vb4[1].z + pr.z * vb4[2].z + pr.w * vb4[3].z;
                O[i][3] += pr.x * vb4[0].w + pr.y * vb4[1].w + pr.z * vb4[2].w + pr.w * vb4[3].w;
            }
        }
    }
#undef LDV

#pragma unroll
    for (int i = 0; i < 4; ++i) {
        const float zinv = 1.0f / z_run[i];
        float4 o4 = make_float4(O[i][0] * zinv, O[i][1] * zinv,
                                O[i][2] * zinv, O[i][3] * zinv);
        *(float4*)(Lout + ((size_t)bh * N_ + q0 + 4 * ty + i) * HD_ + txo) = o4;
    }
    if (tx == 0) {
#pragma unroll
        for (int i = 0; i < 4; ++i) {
            const int r = 4 * ty + i;
            Mrow[(size_t)bh * N_ + q0 + r] = m_run[i];
            Zrow[(size_t)bh * N_ + q0 + r] = z_run[i];
        }
    }
}

// ---------------------------------------------------------------------------
// K6: recompute final scores from k2 + saved (m, Z); write fp32 attn.
// grid (16, 96) x 256.
// ---------------------------------------------------------------------------
__global__ __launch_bounds__(256)
void attn_out(const float* __restrict__ K2v, const float* __restrict__ Mrow,
              const float* __restrict__ Zrow, float* __restrict__ A)
{
    __shared__ float Qs[64][68];
    __shared__ float Ks[64][68];
    const int tid = threadIdx.x;
    const int tx = tid & 15, ty = tid >> 4;
    const int bh = blockIdx.y;
    const int q0 = blockIdx.x * 64;
    const float* k2b = K2v + (size_t)bh * N_ * HD_;

    {
        int e = tid;
#pragma unroll
        for (int t = 0; t < 4; ++t, e += 256) {
            int r = e >> 4, c4 = (e & 15) << 2;
            *(float4*)&Qs[r][c4] =
                *(const float4*)(k2b + (size_t)(q0 + r) * HD_ + c4);
        }
    }
    float mi[4], zi[4];
#pragma unroll
    for (int i = 0; i < 4; ++i) {
        const int r = q0 + 4 * ty + i;
        mi[i] = Mrow[(size_t)bh * N_ + r];
        zi[i] = 1.0f / Zrow[(size_t)bh * N_ + r];
    }

    for (int kt = 0; kt < 16; ++kt) {
        __syncthreads();
        {
            int e = tid;
#pragma unroll
            for (int t = 0; t < 4; ++t, e += 256) {
                int r = e >> 4, c4 = (e & 15) << 2;
                *(float4*)&Ks[r][c4] =
                    *(const float4*)(k2b + (size_t)(kt * 64 + r) * HD_ + c4);
            }
        }
        __syncthreads();

        float S[4][4] = {};
#pragma unroll 4
        for (int d4 = 0; d4 < 16; ++d4) {
            float4 a[4], b[4];
#pragma unroll
            for (int i = 0; i < 4; ++i) a[i] = *(const float4*)&Qs[4 * ty + i][4 * d4];
#pragma unroll
            for (int j = 0; j < 4; ++j) b[j] = *(const float4*)&Ks[tx + 16 * j][4 * d4];
#pragma unroll
            for (int i = 0; i < 4; ++i)
#pragma unroll
                for (int j = 0; j < 4; ++j)
                    S[i][j] += a[i].x * b[j].x + a[i].y * b[j].y +
                               a[i].z * b[j].z + a[i].w * b[j].w;
        }
#pragma unroll
        for (int i = 0; i < 4; ++i) {
            float* arow = A + ((size_t)(bh * N_ + q0 + 4 * ty + i)) * N_ + kt * 64;
#pragma unroll
            for (int j = 0; j < 4; ++j)
                arow[tx + 16 * j] = __expf(S[i][j] * SCALE_ - mi[i]) * zi[i];
        }
    }
}

// ---------------------------------------------------------------------------
// K7 tiled proj: out = l_t @ W_proj + b_proj (fp32).
// grid (768/64=12, 8192/64=128), block 256.
// ---------------------------------------------------------------------------
__global__ __launch_bounds__(256)
void proj_gemm(const float* __restrict__ Lb, const float* __restrict__ W,
               const float* __restrict__ bias, float* __restrict__ Out)
{
    __shared__ float As[64][17];
    __shared__ float Bs[16][68];
    const int tid = threadIdx.x;
    const int tx = tid & 15, ty = tid >> 4;
    const int m0 = blockIdx.y * 64;
    const int c0 = blockIdx.x * 64;
    const int ar = tid >> 2, ak4 = (tid & 3) << 2;
    const int bk = tid >> 4, bc4 = (tid & 15) << 2;

    const int am = m0 + ar;
    const int ab = am >> 10, an = am & 1023;

    float acc[4][4] = {};

    for (int kt = 0; kt < 48; ++kt) {
        __syncthreads();
        {
            const int kk0 = kt * 16 + ak4;
            const int h = kk0 >> 6, d = kk0 & 63;
            float4 av = *(const float4*)(Lb + ((size_t)(ab * H_ + h) * N_ + an) * HD_ + d);
            As[ar][ak4 + 0] = av.x; As[ar][ak4 + 1] = av.y;
            As[ar][ak4 + 2] = av.z; As[ar][ak4 + 3] = av.w;
        }
        *(float4*)&Bs[bk][bc4] =
            *(const float4*)(W + (size_t)(kt * 16 + bk) * C_ + c0 + bc4);
        __syncthreads();
#pragma unroll
        for (int kk = 0; kk < 16; ++kk) {
            float a_[4];
#pragma unroll
            for (int i = 0; i < 4; ++i) a_[i] = As[4 * ty + i][kk];
            float4 b_ = *(const float4*)&Bs[kk][4 * tx];
#pragma unroll
            for (int i = 0; i < 4; ++i) {
                acc[i][0] += a_[i] * b_.x;
                acc[i][1] += a_[i] * b_.y;
                acc[i][2] += a_[i] * b_.z;
                acc[i][3] += a_[i] * b_.w;
            }
        }
    }

    const int cb = c0 + 4 * tx;
    const float b0 = bias[cb + 0], b1 = bias[cb + 1];
    const float b2 = bias[cb + 2], b3 = bias[cb + 3];
#pragma unroll
    for (int i = 0; i < 4; ++i) {
        const int m = m0 + 4 * ty + i;
        float4 o;
        o.x = acc[i][0] + b0;
        o.y = acc[i][1] + b1;
        o.z = acc[i][2] + b2;
        o.w = acc[i][3] + b3;
        *(float4*)(Out + (size_t)m * C_ + cb) = o;
    }
}

// ---------------------------------------------------------------------------
// d_out is FLOAT32: out = d_out[0 .. 6291456), attn = d_out[6291456 .. ).
// ws (floats): kb@0, vb@SZ, lb@2SZ, yb@3SZ, k2b@4SZ, mu@5SZ(128), rowm, rowz.
// ---------------------------------------------------------------------------
extern "C" void kernel_launch(void* const* d_in, const int* in_sizes, int n_in,
                              void* d_out, int out_size, void* d_ws, size_t ws_size,
                              hipStream_t stream)
{
    (void)in_sizes; (void)n_in; (void)out_size; (void)ws_size;

    const float* x  = (const float*)d_in[0];
    const float* Wq = (const float*)d_in[1];
    const float* bq = (const float*)d_in[2];
    const float* Wp = (const float*)d_in[3];
    const float* bp = (const float*)d_in[4];

    float* out_f  = (float*)d_out;
    float* attn_f = out_f + (size_t)B_ * N_ * C_;

    const size_t SZ = (size_t)BH_ * N_ * HD_;   // 6,291,456 floats
    float* ws   = (float*)d_ws;
    float* kb   = ws;
    float* vb   = ws + SZ;
    float* lb   = ws + 2 * SZ;
    float* yb   = ws + 3 * SZ;
    float* k2b  = ws + 4 * SZ;
    float* mu   = ws + 5 * SZ;                  // 96 floats (pad 128)
    float* rowm = mu + 128;                     // BH*N
    float* rowz = rowm + (size_t)BH_ * N_;      // BH*N

    hipMemsetAsync(lb, 0, SZ * sizeof(float), stream);
    hipMemsetAsync(yb, 0, SZ * sizeof(float), stream);

    qkv_gemm<<<dim3(24, 128), 256, 0, stream>>>(x, Wq, bq, kb, vb);
    musum<<<96, 256, 0, stream>>>(kb, mu);

    for (int it = 0; it <= NIT_; ++it) {
        ew_sk2<<<24576, 256, 0, stream>>>(kb, lb, yb, mu, k2b);
        flash<<<dim3(16, 96), 256, 0, stream>>>(k2b, vb, lb, rowm, rowz);
        if (it < NIT_)
            ew_y<<<24576, 256, 0, stream>>>(yb, k2b, lb, mu);
    }

    attn_out<<<dim3(16, 96), 256, 0, stream>>>(k2b, rowm, rowz, attn_f);
    proj_gemm<<<dim3(12, 128), 256, 0, stream>>>(lb, Wp, bp, out_f);
}

// Round 5
// 4228.469 us; speedup vs baseline: 8.9644x; 8.9644x over previous
//
#include <hip/hip_runtime.h>

#define B_   8
#define N_   1024
#define C_   768
#define H_   12
#define HD_  64
#define BH_  96
#define SCALE_ 0.125f
#define NIT_ 5

// ---------------------------------------------------------------------------
// K1 tiled: qkv = x @ W_qkv + b_qkv (fp32), scattered into k/v [B,H,N,HD].
// grid (1536/64=24, 8192/64=128), block 256 (16x16 logical, 4x4 per thread).
// ---------------------------------------------------------------------------
__global__ __launch_bounds__(256)
void qkv_gemm(const float* __restrict__ X, const float* __restrict__ W,
              const float* __restrict__ bias,
              float* __restrict__ Kb, float* __restrict__ Vb)
{
    __shared__ float As[64][17];
    __shared__ float Bs[16][68];
    const int tid = threadIdx.x;
    const int tx = tid & 15, ty = tid >> 4;
    const int m0 = blockIdx.y * 64;
    const int c0 = blockIdx.x * 64;      // [0, 1536)
    const int ar = tid >> 2, ak4 = (tid & 3) << 2;
    const int bk = tid >> 4, bc4 = (tid & 15) << 2;

    float acc[4][4] = {};

    for (int kt = 0; kt < 48; ++kt) {
        __syncthreads();
        float4 av = *(const float4*)(X + (size_t)(m0 + ar) * C_ + kt * 16 + ak4);
        As[ar][ak4 + 0] = av.x; As[ar][ak4 + 1] = av.y;
        As[ar][ak4 + 2] = av.z; As[ar][ak4 + 3] = av.w;
        *(float4*)&Bs[bk][bc4] =
            *(const float4*)(W + (size_t)(kt * 16 + bk) * (2 * C_) + c0 + bc4);
        __syncthreads();
#pragma unroll
        for (int kk = 0; kk < 16; ++kk) {
            float a_[4];
#pragma unroll
            for (int i = 0; i < 4; ++i) a_[i] = As[4 * ty + i][kk];
            float4 b_ = *(const float4*)&Bs[kk][4 * tx];
#pragma unroll
            for (int i = 0; i < 4; ++i) {
                acc[i][0] += a_[i] * b_.x;
                acc[i][1] += a_[i] * b_.y;
                acc[i][2] += a_[i] * b_.z;
                acc[i][3] += a_[i] * b_.w;
            }
        }
    }

    const int cbase = c0 + 4 * tx;               // within [c0, c0+64)
    const int h = (c0 % C_) >> 6;                // head is constant per block
    float* tgt = (c0 < C_) ? Kb : Vb;
    const float b0 = bias[cbase + 0], b1 = bias[cbase + 1];
    const float b2 = bias[cbase + 2], b3 = bias[cbase + 3];
#pragma unroll
    for (int i = 0; i < 4; ++i) {
        int m = m0 + 4 * ty + i;
        int b = m >> 10, n = m & 1023;
        float4 o;
        o.x = acc[i][0] + b0;
        o.y = acc[i][1] + b1;
        o.z = acc[i][2] + b2;
        o.w = acc[i][3] + b3;
        *(float4*)(tgt + ((size_t)(b * H_ + h) * N_ + n) * HD_ + 4 * tx) = o;
    }
}

// ---------------------------------------------------------------------------
// K2: mu[bh] = (N*C/4) / sum|k| per (b,h).
// ---------------------------------------------------------------------------
__global__ __launch_bounds__(256)
void musum(const float* __restrict__ Kb, float* __restrict__ mu)
{
    const int bh = blockIdx.x;
    const int tid = threadIdx.x;
    const float* p = Kb + (size_t)bh * (N_ * HD_);
    float s = 0.0f;
    for (int i = tid; i < N_ * HD_; i += 256) s += fabsf(p[i]);
    for (int off = 32; off; off >>= 1) s += __shfl_down(s, off, 64);
    __shared__ float red[4];
    if ((tid & 63) == 0) red[tid >> 6] = s;
    __syncthreads();
    if (tid == 0)
        mu[bh] = (float)(N_ * C_ / 4.0) / (red[0] + red[1] + red[2] + red[3]);
}

// ---------------------------------------------------------------------------
// K3: t = k - l + y/mu; s = soft_threshold(t, 4*mu); k2 = k - s - y/mu
// ---------------------------------------------------------------------------
__global__ __launch_bounds__(256)
void ew_sk2(const float* __restrict__ Kb, const float* __restrict__ Lb,
            const float* __restrict__ Yb, const float* __restrict__ mu,
            float* __restrict__ K2b)
{
    const int i = blockIdx.x * 256 + threadIdx.x;
    const int bh = i >> 16;
    const float m = mu[bh];
    const float lm = 4.0f * m;
    const float yom = Yb[i] / m;
    const float kv = Kb[i];
    const float t = kv - Lb[i] + yom;
    const float s = (t >= lm) ? (t - lm) : ((t <= -lm) ? (t + lm) : 0.0f);
    K2b[i] = kv - s - yom;
}

// ---------------------------------------------------------------------------
// K5: y_new = 2*y + mu*(k2 - l)
// ---------------------------------------------------------------------------
__global__ __launch_bounds__(256)
void ew_y(float* __restrict__ Yb, const float* __restrict__ K2b,
          const float* __restrict__ Lb, const float* __restrict__ mu)
{
    const int i = blockIdx.x * 256 + threadIdx.x;
    const int bh = i >> 16;
    const float m = mu[bh];
    Yb[i] = 2.0f * Yb[i] + m * (K2b[i] - Lb[i]);
}

// ---------------------------------------------------------------------------
// K4 flash v6: EXACT R0 structure except:
//  - Vs LDS buffer removed; PV reads V from global via NAMED float4 scalars
//    (v0..v3) adjacent to use — the exact load style proven scratch-free in
//    R0 and v3.  NO arrays, NO macros, NO double-buffering.
//  - m/z in registers (proven in R2-R4 passes, identical math).
//  - LDS 52.7 -> 34.8 KB (Qs + Ks-aliased-Ps) -> 4 blocks/CU.
// FMA accumulation orders identical to R0 -> numerics preserved.
// grid (16, 96) x 256.
// ---------------------------------------------------------------------------
__global__ __launch_bounds__(256)
void flash(const float* __restrict__ K2v, const float* __restrict__ Vv,
           float* __restrict__ Lout, float* __restrict__ Mrow,
           float* __restrict__ Zrow)
{
    __shared__ float Qs[64][68];
    __shared__ float Ks[64][68];          // doubles as Ps after S-compute

    const int tid = threadIdx.x;
    const int tx = tid & 15, ty = tid >> 4;
    const int bh = blockIdx.y;
    const int q0 = blockIdx.x * 64;
    const float* __restrict__ k2b = K2v + (size_t)bh * N_ * HD_;
    const float* __restrict__ vbp = Vv  + (size_t)bh * N_ * HD_;

    {
        int e = tid;
#pragma unroll
        for (int t = 0; t < 4; ++t, e += 256) {
            int r = e >> 4, c4 = (e & 15) << 2;
            *(float4*)&Qs[r][c4] =
                *(const float4*)(k2b + (size_t)(q0 + r) * HD_ + c4);
        }
    }

    float m_run[4], z_run[4];
#pragma unroll
    for (int i = 0; i < 4; ++i) { m_run[i] = -1e30f; z_run[i] = 0.0f; }

    float O[4][4];
#pragma unroll
    for (int i = 0; i < 4; ++i)
#pragma unroll
        for (int j = 0; j < 4; ++j) O[i][j] = 0.0f;

    for (int kt = 0; kt < 16; ++kt) {
        __syncthreads();   // prev PV's Ps reads done; Qs init visible (kt=0)
        {
            int e = tid;
#pragma unroll
            for (int t = 0; t < 4; ++t, e += 256) {
                int r = e >> 4, c4 = (e & 15) << 2;
                *(float4*)&Ks[r][c4] =
                    *(const float4*)(k2b + (size_t)(kt * 64 + r) * HD_ + c4);
            }
        }
        __syncthreads();

        // S[i][j] = (Q row 4ty+i) . (K row tx+16j)   -- identical to R0
        float S[4][4] = {};
#pragma unroll 4
        for (int d4 = 0; d4 < 16; ++d4) {
            float4 a[4], b[4];
#pragma unroll
            for (int i = 0; i < 4; ++i) a[i] = *(const float4*)&Qs[4 * ty + i][4 * d4];
#pragma unroll
            for (int j = 0; j < 4; ++j) b[j] = *(const float4*)&Ks[tx + 16 * j][4 * d4];
#pragma unroll
            for (int i = 0; i < 4; ++i)
#pragma unroll
                for (int j = 0; j < 4; ++j)
                    S[i][j] += a[i].x * b[j].x + a[i].y * b[j].y +
                               a[i].z * b[j].z + a[i].w * b[j].w;
        }
#pragma unroll
        for (int i = 0; i < 4; ++i)
#pragma unroll
            for (int j = 0; j < 4; ++j) S[i][j] *= SCALE_;

        float mt[4];
#pragma unroll
        for (int i = 0; i < 4; ++i)
            mt[i] = fmaxf(fmaxf(S[i][0], S[i][1]), fmaxf(S[i][2], S[i][3]));
        for (int off = 8; off; off >>= 1)
#pragma unroll
            for (int i = 0; i < 4; ++i)
                mt[i] = fmaxf(mt[i], __shfl_xor(mt[i], off, 16));

        float alpha[4], zs[4];
#pragma unroll
        for (int i = 0; i < 4; ++i) {
            const float mnew = fmaxf(m_run[i], mt[i]);
            alpha[i] = __expf(m_run[i] - mnew);
            m_run[i] = mnew;
            zs[i] = 0.0f;
#pragma unroll
            for (int j = 0; j < 4; ++j) {
                S[i][j] = __expf(S[i][j] - mnew);
                zs[i] += S[i][j];
            }
        }
        for (int off = 8; off; off >>= 1)
#pragma unroll
            for (int i = 0; i < 4; ++i) zs[i] += __shfl_xor(zs[i], off, 16);
#pragma unroll
        for (int i = 0; i < 4; ++i) {
            z_run[i] = z_run[i] * alpha[i] + zs[i];
#pragma unroll
            for (int j = 0; j < 4; ++j) O[i][j] *= alpha[i];
        }

        __syncthreads();   // all Ks reads complete before Ps overwrites it

#pragma unroll
        for (int i = 0; i < 4; ++i)
#pragma unroll
            for (int j = 0; j < 4; ++j)
                Ks[4 * ty + i][tx + 16 * j] = S[i][j];   // Ps := Ks storage

        __syncthreads();   // Ps fully written

        // O[i][c] += sum_m Ps[4ty+i][m] * V[m][4tx+c]; V from global,
        // named scalar loads adjacent to use (v3-proven pattern).
        // FMA order identical to R0.
#pragma unroll 4
        for (int j4 = 0; j4 < 16; ++j4) {
            const float* vc = vbp + (size_t)(kt * 64 + 4 * j4) * HD_ + 4 * tx;
            const float4 v0 = *(const float4*)(vc);
            const float4 v1 = *(const float4*)(vc + HD_);
            const float4 v2 = *(const float4*)(vc + 2 * HD_);
            const float4 v3 = *(const float4*)(vc + 3 * HD_);
#pragma unroll
            for (int i = 0; i < 4; ++i) {
                const float4 pr = *(const float4*)&Ks[4 * ty + i][4 * j4];
                O[i][0] += pr.x * v0.x + pr.y * v1.x + pr.z * v2.x + pr.w * v3.x;
                O[i][1] += pr.x * v0.y + pr.y * v1.y + pr.z * v2.y + pr.w * v3.y;
                O[i][2] += pr.x * v0.z + pr.y * v1.z + pr.z * v2.z + pr.w * v3.z;
                O[i][3] += pr.x * v0.w + pr.y * v1.w + pr.z * v2.w + pr.w * v3.w;
            }
        }
    }

#pragma unroll
    for (int i = 0; i < 4; ++i) {
        const float zinv = 1.0f / z_run[i];
        float4 o4 = make_float4(O[i][0] * zinv, O[i][1] * zinv,
                                O[i][2] * zinv, O[i][3] * zinv);
        *(float4*)(Lout + ((size_t)bh * N_ + q0 + 4 * ty + i) * HD_ + 4 * tx) = o4;
    }
    if (tx == 0) {
#pragma unroll
        for (int i = 0; i < 4; ++i) {
            const int r = 4 * ty + i;
            Mrow[(size_t)bh * N_ + q0 + r] = m_run[i];
            Zrow[(size_t)bh * N_ + q0 + r] = z_run[i];
        }
    }
}

// ---------------------------------------------------------------------------
// K6: recompute final scores from k2 + saved (m, Z); write fp32 attn.
// grid (16, 96) x 256.
// ---------------------------------------------------------------------------
__global__ __launch_bounds__(256)
void attn_out(const float* __restrict__ K2v, const float* __restrict__ Mrow,
              const float* __restrict__ Zrow, float* __restrict__ A)
{
    __shared__ float Qs[64][68];
    __shared__ float Ks[64][68];
    const int tid = threadIdx.x;
    const int tx = tid & 15, ty = tid >> 4;
    const int bh = blockIdx.y;
    const int q0 = blockIdx.x * 64;
    const float* k2b = K2v + (size_t)bh * N_ * HD_;

    {
        int e = tid;
#pragma unroll
        for (int t = 0; t < 4; ++t, e += 256) {
            int r = e >> 4, c4 = (e & 15) << 2;
            *(float4*)&Qs[r][c4] =
                *(const float4*)(k2b + (size_t)(q0 + r) * HD_ + c4);
        }
    }
    float mi[4], zi[4];
#pragma unroll
    for (int i = 0; i < 4; ++i) {
        const int r = q0 + 4 * ty + i;
        mi[i] = Mrow[(size_t)bh * N_ + r];
        zi[i] = 1.0f / Zrow[(size_t)bh * N_ + r];
    }

    for (int kt = 0; kt < 16; ++kt) {
        __syncthreads();
        {
            int e = tid;
#pragma unroll
            for (int t = 0; t < 4; ++t, e += 256) {
                int r = e >> 4, c4 = (e & 15) << 2;
                *(float4*)&Ks[r][c4] =
                    *(const float4*)(k2b + (size_t)(kt * 64 + r) * HD_ + c4);
            }
        }
        __syncthreads();

        float S[4][4] = {};
#pragma unroll 4
        for (int d4 = 0; d4 < 16; ++d4) {
            float4 a[4], b[4];
#pragma unroll
            for (int i = 0; i < 4; ++i) a[i] = *(const float4*)&Qs[4 * ty + i][4 * d4];
#pragma unroll
            for (int j = 0; j < 4; ++j) b[j] = *(const float4*)&Ks[tx + 16 * j][4 * d4];
#pragma unroll
            for (int i = 0; i < 4; ++i)
#pragma unroll
                for (int j = 0; j < 4; ++j)
                    S[i][j] += a[i].x * b[j].x + a[i].y * b[j].y +
                               a[i].z * b[j].z + a[i].w * b[j].w;
        }
#pragma unroll
        for (int i = 0; i < 4; ++i) {
            float* arow = A + ((size_t)(bh * N_ + q0 + 4 * ty + i)) * N_ + kt * 64;
#pragma unroll
            for (int j = 0; j < 4; ++j)
                arow[tx + 16 * j] = __expf(S[i][j] * SCALE_ - mi[i]) * zi[i];
        }
    }
}

// ---------------------------------------------------------------------------
// K7 tiled proj: out = l_t @ W_proj + b_proj (fp32).
// grid (768/64=12, 8192/64=128), block 256.
// ---------------------------------------------------------------------------
__global__ __launch_bounds__(256)
void proj_gemm(const float* __restrict__ Lb, const float* __restrict__ W,
               const float* __restrict__ bias, float* __restrict__ Out)
{
    __shared__ float As[64][17];
    __shared__ float Bs[16][68];
    const int tid = threadIdx.x;
    const int tx = tid & 15, ty = tid >> 4;
    const int m0 = blockIdx.y * 64;
    const int c0 = blockIdx.x * 64;
    const int ar = tid >> 2, ak4 = (tid & 3) << 2;
    const int bk = tid >> 4, bc4 = (tid & 15) << 2;

    const int am = m0 + ar;
    const int ab = am >> 10, an = am & 1023;

    float acc[4][4] = {};

    for (int kt = 0; kt < 48; ++kt) {
        __syncthreads();
        {
            const int kk0 = kt * 16 + ak4;
            const int h = kk0 >> 6, d = kk0 & 63;
            float4 av = *(const float4*)(Lb + ((size_t)(ab * H_ + h) * N_ + an) * HD_ + d);
            As[ar][ak4 + 0] = av.x; As[ar][ak4 + 1] = av.y;
            As[ar][ak4 + 2] = av.z; As[ar][ak4 + 3] = av.w;
        }
        *(float4*)&Bs[bk][bc4] =
            *(const float4*)(W + (size_t)(kt * 16 + bk) * C_ + c0 + bc4);
        __syncthreads();
#pragma unroll
        for (int kk = 0; kk < 16; ++kk) {
            float a_[4];
#pragma unroll
            for (int i = 0; i < 4; ++i) a_[i] = As[4 * ty + i][kk];
            float4 b_ = *(const float4*)&Bs[kk][4 * tx];
#pragma unroll
            for (int i = 0; i < 4; ++i) {
                acc[i][0] += a_[i] * b_.x;
                acc[i][1] += a_[i] * b_.y;
                acc[i][2] += a_[i] * b_.z;
                acc[i][3] += a_[i] * b_.w;
            }
        }
    }

    const int cb = c0 + 4 * tx;
    const float b0 = bias[cb + 0], b1 = bias[cb + 1];
    const float b2 = bias[cb + 2], b3 = bias[cb + 3];
#pragma unroll
    for (int i = 0; i < 4; ++i) {
        const int m = m0 + 4 * ty + i;
        float4 o;
        o.x = acc[i][0] + b0;
        o.y = acc[i][1] + b1;
        o.z = acc[i][2] + b2;
        o.w = acc[i][3] + b3;
        *(float4*)(Out + (size_t)m * C_ + cb) = o;
    }
}

// ---------------------------------------------------------------------------
// d_out is FLOAT32: out = d_out[0 .. 6291456), attn = d_out[6291456 .. ).
// ws (floats): kb@0, vb@SZ, lb@2SZ, yb@3SZ, k2b@4SZ, mu@5SZ(128), rowm, rowz.
// ---------------------------------------------------------------------------
extern "C" void kernel_launch(void* const* d_in, const int* in_sizes, int n_in,
                              void* d_out, int out_size, void* d_ws, size_t ws_size,
                              hipStream_t stream)
{
    (void)in_sizes; (void)n_in; (void)out_size; (void)ws_size;

    const float* x  = (const float*)d_in[0];
    const float* Wq = (const float*)d_in[1];
    const float* bq = (const float*)d_in[2];
    const float* Wp = (const float*)d_in[3];
    const float* bp = (const float*)d_in[4];

    float* out_f  = (float*)d_out;
    float* attn_f = out_f + (size_t)B_ * N_ * C_;

    const size_t SZ = (size_t)BH_ * N_ * HD_;   // 6,291,456 floats
    float* ws   = (float*)d_ws;
    float* kb   = ws;
    float* vb   = ws + SZ;
    float* lb   = ws + 2 * SZ;
    float* yb   = ws + 3 * SZ;
    float* k2b  = ws + 4 * SZ;
    float* mu   = ws + 5 * SZ;                  // 96 floats (pad 128)
    float* rowm = mu + 128;                     // BH*N
    float* rowz = rowm + (size_t)BH_ * N_;      // BH*N

    hipMemsetAsync(lb, 0, SZ * sizeof(float), stream);
    hipMemsetAsync(yb, 0, SZ * sizeof(float), stream);

    qkv_gemm<<<dim3(24, 128), 256, 0, stream>>>(x, Wq, bq, kb, vb);
    musum<<<96, 256, 0, stream>>>(kb, mu);

    for (int it = 0; it <= NIT_; ++it) {
        ew_sk2<<<24576, 256, 0, stream>>>(kb, lb, yb, mu, k2b);
        flash<<<dim3(16, 96), 256, 0, stream>>>(k2b, vb, lb, rowm, rowz);
        if (it < NIT_)
            ew_y<<<24576, 256, 0, stream>>>(yb, k2b, lb, mu);
    }

    attn_out<<<dim3(16, 96), 256, 0, stream>>>(k2b, rowm, rowz, attn_f);
    proj_gemm<<<dim3(12, 128), 256, 0, stream>>>(lb, Wp, bp, out_f);
}